// Round 14
// baseline (100.899 us; speedup 1.0000x reference)
//
#include <hip/hip_runtime.h>
#include <hip/hip_cooperative_groups.h>

namespace cg = cooperative_groups;

#define EPSF 1e-6f
#define TPB 256
#define KMAXC 21           // seg channels (K = 21)
#define NGR 21             // gt rows staged
#define RW 72              // bf16 row stride per wave slice (144 B; 16B-aligned frags)
#define SLICE (KMAXC * RW) // 1512 bf16 per matrix per wave
#define TBL 1024           // 32x32 cells per per-block table (4 KB stride)
#define COOP_BLK 512       // co-resident: 24 KB LDS -> 6 blocks/CU >= 2/CU needed

typedef float  f32x4  __attribute__((ext_vector_type(4)));
typedef float  f32x16 __attribute__((ext_vector_type(16)));
typedef __bf16 bf16x8 __attribute__((ext_vector_type(8)));
typedef __bf16 bf16x4 __attribute__((ext_vector_type(4)));

struct GroupRegs { f32x4 s[6]; int4 g[6]; };

// issue all 12 vector loads for one 64-pixel group (stay in flight together)
__device__ __forceinline__ void issue_loads(const float* __restrict__ seg,
                                            const int* __restrict__ gt,
                                            int N, int GROWS, int p0, int lane,
                                            GroupRegs& r) {
    const f32x4* s4 = (const f32x4*)(seg + (size_t)p0 * KMAXC);
    #pragma unroll
    for (int q = 0; q < 6; ++q) {
        const int i4 = lane + (q << 6);            // f32x4 idx in [0,336)
        f32x4 v = {0.5f, 0.5f, 0.5f, 0.5f};
        if (i4 < 336) v = s4[i4];
        r.s[q] = v;
    }
    #pragma unroll
    for (int q = 0; q < 6; ++q) {
        const int i4 = lane + (q << 6);
        int4 gv = {0, 0, 0, 0};
        if (i4 < 336) {
            int row = i4 >> 4;                     // 0..20 (16 int4 per row)
            row = (row < GROWS) ? row : (GROWS - 1);
            gv = *(const int4*)(gt + (size_t)row * N + p0 + ((i4 & 15) << 2));
        }
        r.g[q] = gv;
    }
}

// log-odds + bf16 scatter to this wave's LDS slice
__device__ __forceinline__ void scatter_group(__bf16* dl, __bf16* ml, int lane,
                                              const GroupRegs& r) {
    #pragma unroll
    for (int q = 0; q < 6; ++q) {
        const int i4 = lane + (q << 6);
        if (i4 < 336) {
            const int lin = i4 << 2;
            int pix = lin / KMAXC;
            int k   = lin - pix * KMAXC;
            #pragma unroll
            for (int c = 0; c < 4; ++c) {
                const float s = r.s[q][c];
                const float dd = __log2f(s + EPSF) - __log2f(1.0f - s + EPSF);
                dl[k * RW + pix] = (__bf16)dd;
                if (++k == KMAXC) { k = 0; ++pix; }
            }
            const int row = i4 >> 4;
            bf16x4 mv;
            mv[0] = (__bf16)(float)(r.g[q].x != 0);
            mv[1] = (__bf16)(float)(r.g[q].y != 0);
            mv[2] = (__bf16)(float)(r.g[q].z != 0);
            mv[3] = (__bf16)(float)(r.g[q].w != 0);
            *(bf16x4*)(ml + row * RW + ((i4 & 15) << 2)) = mv;
        }
    }
}

// 4x MFMA over one 64-pixel group (K-dim = pixels)
__device__ __forceinline__ void mfma_group(const __bf16* dl, const __bf16* ml,
                                           int lane, int K, f32x16& acc) {
    const int r31  = lane & 31;
    const int rowA = (r31 < K)   ? r31 : (K - 1);   // clamp: dup rows discarded
    const int rowB = (r31 < NGR) ? r31 : (NGR - 1);
    const int off  = (lane >> 5) << 3;
    const __bf16* pa = dl + rowA * RW + off;
    const __bf16* pb = ml + rowB * RW + off;
    #pragma unroll
    for (int i = 0; i < 4; ++i) {
        const bf16x8 af = *(const bf16x8*)(pa + i * 16);
        const bf16x8 bf = *(const bf16x8*)(pb + i * 16);
        acc = __builtin_amdgcn_mfma_f32_32x32x16_bf16(af, bf, acc, 0, 0, 0);
    }
}

// generic per-element path (tail group / odd K)
__device__ __forceinline__ void generic_group(const float* __restrict__ seg,
                                              const int* __restrict__ gt,
                                              __bf16* dl, __bf16* ml, int lane,
                                              int N, int K, int GROWS, int p0) {
    for (int i = lane; i < K * 64; i += 64) {
        const int pix = i / K, k = i - pix * K;
        const float s = (p0 + pix < N) ? seg[(size_t)(p0 + pix) * K + k] : 0.5f;
        const float dd = __log2f(s + EPSF) - __log2f(1.0f - s + EPSF);
        if (k < KMAXC) dl[k * RW + pix] = (__bf16)dd;   // s=0.5 -> d=0 (inert)
    }
    for (int i = lane; i < NGR * 64; i += 64) {
        const int row = i >> 6, c = i & 63;
        int val = 0;
        if (row < GROWS && p0 + c < N) val = (gt[(size_t)row * N + p0 + c] != 0);
        ml[row * RW + c] = (__bf16)(float)val;
    }
}

// Fused cooperative kernel:
//  phase 1: A[k,g] = sum_n d[k,n]*gi[g,n] -> per-block private tables
//  grid.sync()
//  phase 2: blocks 0..K-1 reduce their k-row over tables (L2-warm), argmax.
__global__ __launch_bounds__(TPB) void msk_coop(
    const float* __restrict__ seg,   // (N, K) row-major
    const int* __restrict__ gt,      // (GROWS, N) row-major
    const int* __restrict__ gpn,     // scalar gt_plane_num
    float* __restrict__ sums,        // NBLK x [TBL] f32 per-block tables
    int* __restrict__ out,           // (K,) int32
    int N, int K, int GROWS, int NGROUP, int NBLK)
{
    const int tid  = threadIdx.x;
    const int lane = tid & 63;
    const int wv   = tid >> 6;

    __shared__ union {
        __bf16 stage[4][2][SLICE];   // [wave][0=d rows [k][px], 1=mask rows [g][px]]
        float  red[4 * TBL];
        struct { float P[8][33]; float A[32]; } fin;
    } u;

    // ================= phase 1: partial GEMM =================
    f32x16 acc = {};
    __bf16* dl = u.stage[wv][0];
    __bf16* ml = u.stage[wv][1];

    const int W  = NBLK * 4;
    const int gw = (int)blockIdx.x * 4 + wv;

    if (K == KMAXC) {
        const int g0 = gw, g1 = gw + W;
        const bool f0 = (g0 < NGROUP) && ((g0 << 6) + 64 <= N);
        const bool f1 = (g1 < NGROUP) && ((g1 << 6) + 64 <= N);
        GroupRegs r0, r1;
        if (f0) issue_loads(seg, gt, N, GROWS, g0 << 6, lane, r0);
        if (f1) issue_loads(seg, gt, N, GROWS, g1 << 6, lane, r1);
        if (f0) { scatter_group(dl, ml, lane, r0); mfma_group(dl, ml, lane, K, acc); }
        if (f1) { scatter_group(dl, ml, lane, r1); mfma_group(dl, ml, lane, K, acc); }
        if (g0 < NGROUP && !f0) {
            generic_group(seg, gt, dl, ml, lane, N, K, GROWS, g0 << 6);
            mfma_group(dl, ml, lane, K, acc);
        }
        if (g1 < NGROUP && !f1) {
            generic_group(seg, gt, dl, ml, lane, N, K, GROWS, g1 << 6);
            mfma_group(dl, ml, lane, K, acc);
        }
        for (int gid = gw + 2 * W; gid < NGROUP; gid += W) {
            const int p0 = gid << 6;
            if (p0 + 64 <= N) {
                GroupRegs r;
                issue_loads(seg, gt, N, GROWS, p0, lane, r);
                scatter_group(dl, ml, lane, r);
            } else {
                generic_group(seg, gt, dl, ml, lane, N, K, GROWS, p0);
            }
            mfma_group(dl, ml, lane, K, acc);
        }
    } else {
        for (int gid = gw; gid < NGROUP; gid += W) {
            generic_group(seg, gt, dl, ml, lane, N, K, GROWS, gid << 6);
            mfma_group(dl, ml, lane, K, acc);
        }
    }

    // cross-wave reduce via canonical LDS layout
    __syncthreads();
    {
        const int col = lane & 31;
        const int rhi = (lane >> 5) << 2;
        #pragma unroll
        for (int r = 0; r < 16; ++r) {
            const int row = (r & 3) + ((r >> 2) << 3) + rhi;   // verified C/D mapping
            u.red[wv * TBL + row * 32 + col] = acc[r];
        }
    }
    __syncthreads();

    // private table write: live rows only; relaxed agent-scope atomic stores
    {
        float* stbl = sums + (size_t)blockIdx.x * TBL;
        const int live = K * 32;
        for (int cell = tid; cell < live; cell += TPB) {
            const float v = u.red[cell] + u.red[TBL + cell]
                          + u.red[2 * TBL + cell] + u.red[3 * TBL + cell];
            __hip_atomic_store(&stbl[cell], v, __ATOMIC_RELAXED,
                               __HIP_MEMORY_SCOPE_AGENT);
        }
    }

    // ================= grid-wide barrier =================
    cg::this_grid().sync();

    // ================= phase 2: reduce + argmax =================
    const int k = (int)blockIdx.x;
    if (k >= K) return;

    const int G = *gpn;
    const int col = tid & 31;
    const int grp = tid >> 5;            // 0..7 table-groups

    const int tpg = NBLK >> 3;           // tables per group (64 at NBLK=512)
    const int t0  = grp * tpg;
    const size_t rowoff = (size_t)k * 32 + col;

    #define AL(T) __hip_atomic_load(&sums[(size_t)(T) * TBL + rowoff], \
                                    __ATOMIC_RELAXED, __HIP_MEMORY_SCOPE_AGENT)
    float v0 = 0.f, v1 = 0.f, v2 = 0.f, v3 = 0.f;
    float v4 = 0.f, v5 = 0.f, v6 = 0.f, v7 = 0.f;
    float v8 = 0.f, v9 = 0.f, va = 0.f, vb = 0.f;
    float vc = 0.f, vd = 0.f, ve = 0.f, vf = 0.f;
    int i = 0;
    for (; i + 16 <= tpg; i += 16) {     // unconditional: 16 loads in flight
        v0 += AL(t0 + i + 0);  v1 += AL(t0 + i + 1);
        v2 += AL(t0 + i + 2);  v3 += AL(t0 + i + 3);
        v4 += AL(t0 + i + 4);  v5 += AL(t0 + i + 5);
        v6 += AL(t0 + i + 6);  v7 += AL(t0 + i + 7);
        v8 += AL(t0 + i + 8);  v9 += AL(t0 + i + 9);
        va += AL(t0 + i + 10); vb += AL(t0 + i + 11);
        vc += AL(t0 + i + 12); vd += AL(t0 + i + 13);
        ve += AL(t0 + i + 14); vf += AL(t0 + i + 15);
    }
    for (; i < tpg; ++i) v0 += AL(t0 + i);
    if (grp < (NBLK & 7)) v1 += AL((NBLK & ~7) + grp);   // leftover tables
    #undef AL
    const float vv = (((v0 + v1) + (v2 + v3)) + ((v4 + v5) + (v6 + v7)))
                   + (((v8 + v9) + (va + vb)) + ((vc + vd) + (ve + vf)));

    __syncthreads();          // LDS union: phase-1 layout dead before reuse
    u.fin.P[grp][col] = vv;
    __syncthreads();
    if (tid < 32) {
        float s = 0.f;
        #pragma unroll
        for (int g2 = 0; g2 < 8; ++g2) s += u.fin.P[g2][tid];
        u.fin.A[tid] = s;
    }
    __syncthreads();

    if (tid == 0) {
        const int GG = (G < 32) ? G : 32;
        float bv; int bg = 0;
        if (GG > 0) {
            bv = u.fin.A[0];
            for (int g = 1; g < GG; ++g) {
                const float v = u.fin.A[g];
                if (v > bv) { bv = v; bg = g; }   // strict '>' keeps first index
            }
        }
        out[k] = bg;
    }
}

extern "C" void kernel_launch(void* const* d_in, const int* in_sizes, int n_in,
                              void* d_out, int out_size, void* d_ws, size_t ws_size,
                              hipStream_t stream) {
    const float* seg = (const float*)d_in[0];
    // d_in[1] (prob) does not affect the reference output
    const int* gt  = (const int*)d_in[2];
    const int* gpn = (const int*)d_in[3];

    int N = in_sizes[1];                    // prob is (N,1)
    int K = in_sizes[0] / N;                // 21
    int GROWS = in_sizes[2] / N;            // 21
    int NGROUP = (N + 63) >> 6;             // 4800 64-px groups

    int NBLK = COOP_BLK;                    // 512 co-resident blocks
    const long long wcap = (long long)(ws_size / (TBL * sizeof(float)));
    if (NBLK > wcap) NBLK = (int)wcap;      // d_ws budget (observed ~256 MB)
    if (NBLK < 1) NBLK = 1;

    float* sums = (float*)d_ws;
    int* outp = (int*)d_out;

    void* args[] = { (void*)&seg, (void*)&gt, (void*)&gpn, (void*)&sums,
                     (void*)&outp, (void*)&N, (void*)&K, (void*)&GROWS,
                     (void*)&NGROUP, (void*)&NBLK };
    hipLaunchCooperativeKernel((const void*)msk_coop, dim3(NBLK), dim3(TPB),
                               args, 0, stream);
}

// Round 15
// 20.862 us; speedup vs baseline: 4.8364x; 4.8364x over previous
//
#include <hip/hip_runtime.h>

#define EPSF 1e-6f
#define TPB 256
#define KMAXC 21           // seg channels (K = 21)
#define RW 72              // bf16 row stride per wave d-slice (144 B; 16B-aligned frags)
#define SLICE (KMAXC * RW) // 1512 bf16 per wave (d only; mask goes direct to frags)
#define TBL 1024           // 32x32 cells per per-block table (4 KB stride)
#define MAXBLK 1152        // 32 K2-groups x 36 tables (exact 8-stream tiling)

typedef float  f32x4  __attribute__((ext_vector_type(4)));
typedef float  f32x16 __attribute__((ext_vector_type(16)));
typedef __bf16 bf16x8 __attribute__((ext_vector_type(8)));

// pack two int !=0 flags into one dword of two bf16 (0.0 / 1.0)
__device__ __forceinline__ unsigned pk01(int lo, int hi) {
    return (lo != 0 ? 0x3F80u : 0u) | (hi != 0 ? 0x3F800000u : 0u);
}

__device__ __forceinline__ bf16x8 mask_frag(const int4& a, const int4& b) {
    union { unsigned w[4]; bf16x8 v; } u;
    u.w[0] = pk01(a.x, a.y);
    u.w[1] = pk01(a.z, a.w);
    u.w[2] = pk01(b.x, b.y);
    u.w[3] = pk01(b.z, b.w);
    return u.v;
}

// K1: A[k,g] = sum_n d[k,n]*gi[g,n], d = log2((s+eps)/(1-s+eps)) in bf16.
// Wave-private; mask B-fragments loaded DIRECTLY from global in MFMA layout
// (no mask LDS); per-block private output tables (no RMW, no zero-init).
__global__ __launch_bounds__(TPB) void msk_main(
    const float* __restrict__ seg,   // (N, K) row-major
    const int* __restrict__ gt,      // (GROWS, N) row-major
    float* __restrict__ sums,        // NBLK x [TBL] f32 per-block tables
    int N, int K, int GROWS, int NGROUP, int NBLK)
{
    const int tid  = threadIdx.x;
    const int lane = tid & 63;
    const int wv   = tid >> 6;

    __shared__ union {
        __bf16 stage[4][SLICE];      // per-wave d rows [k][px]
        float  red[4 * TBL];
    } u;

    f32x16 acc = {};
    __bf16* dl = u.stage[wv];

    const int W  = NBLK * 4;
    const int gw = (int)blockIdx.x * 4 + wv;

    const int r31   = lane & 31;
    const int rowA  = (r31 < K) ? r31 : (K - 1);         // clamp: dup rows discarded
    const int rowM  = (r31 < GROWS) ? r31 : (GROWS - 1); // clamp: dup cols discarded
    const int half8 = (lane >> 5) << 3;
    const __bf16* pa = dl + rowA * RW + half8;

    for (int gid = gw; gid < NGROUP; gid += W) {
        const int p0 = gid << 6;
        bf16x8 bfrag[4];

        if (K == KMAXC && p0 + 64 <= N) {
            // ---- mask fragment loads: 8 int4 straight into MFMA B layout ----
            const int* gb = gt + (size_t)rowM * N + p0 + half8;
            const int4 m0 = *(const int4*)(gb +  0), m1 = *(const int4*)(gb +  4);
            const int4 m2 = *(const int4*)(gb + 16), m3 = *(const int4*)(gb + 20);
            const int4 m4 = *(const int4*)(gb + 32), m5 = *(const int4*)(gb + 36);
            const int4 m6 = *(const int4*)(gb + 48), m7 = *(const int4*)(gb + 52);

            // ---- seg loads: 6 coalesced f32x4 per lane ----
            f32x4 sreg[6];
            const f32x4* s4 = (const f32x4*)(seg + (size_t)p0 * KMAXC);
            #pragma unroll
            for (int q = 0; q < 6; ++q) {
                const int i4 = lane + (q << 6);          // f32x4 idx in [0,336)
                f32x4 v = {0.5f, 0.5f, 0.5f, 0.5f};
                if (i4 < 336) v = s4[i4];
                sreg[q] = v;
            }

            // convert mask while seg loads drain
            bfrag[0] = mask_frag(m0, m1);
            bfrag[1] = mask_frag(m2, m3);
            bfrag[2] = mask_frag(m4, m5);
            bfrag[3] = mask_frag(m6, m7);

            // ---- scatter d (log-odds, bf16) to this wave's LDS slice ----
            #pragma unroll
            for (int q = 0; q < 6; ++q) {
                const int i4 = lane + (q << 6);
                if (i4 < 336) {
                    const int lin = i4 << 2;
                    int pix = lin / KMAXC;
                    int k   = lin - pix * KMAXC;
                    #pragma unroll
                    for (int c = 0; c < 4; ++c) {
                        const float s = sreg[q][c];
                        const float dd = __log2f(s + EPSF) - __log2f(1.0f - s + EPSF);
                        dl[k * RW + pix] = (__bf16)dd;
                        if (++k == KMAXC) { k = 0; ++pix; }
                    }
                }
            }
        } else {
            // ---- generic fallback (tail group / odd K), correctness only ----
            for (int i = lane; i < K * 64; i += 64) {
                const int pix = i / K, k = i - pix * K;
                const float s = (p0 + pix < N) ? seg[(size_t)(p0 + pix) * K + k] : 0.5f;
                const float dd = __log2f(s + EPSF) - __log2f(1.0f - s + EPSF);
                if (k < KMAXC) dl[k * RW + pix] = (__bf16)dd;  // s=0.5 -> d=0 (inert)
            }
            #pragma unroll
            for (int i = 0; i < 4; ++i) {
                unsigned w[4];
                #pragma unroll
                for (int e = 0; e < 4; ++e) {
                    const int pA = p0 + 16 * i + half8 + 2 * e;
                    const int va = (pA < N) ? gt[(size_t)rowM * N + pA] : 0;
                    const int vb = (pA + 1 < N) ? gt[(size_t)rowM * N + pA + 1] : 0;
                    w[e] = pk01(va, vb);
                }
                union { unsigned ww[4]; bf16x8 v; } cvt;
                cvt.ww[0] = w[0]; cvt.ww[1] = w[1];
                cvt.ww[2] = w[2]; cvt.ww[3] = w[3];
                bfrag[i] = cvt.v;
            }
        }

        // ---- 4x MFMA over the 64-px group (K-dim = pixels) ----
        #pragma unroll
        for (int i = 0; i < 4; ++i) {
            const bf16x8 af = *(const bf16x8*)(pa + i * 16);
            acc = __builtin_amdgcn_mfma_f32_32x32x16_bf16(af, bfrag[i], acc, 0, 0, 0);
        }
    }

    // ---- cross-wave reduce via canonical LDS layout ----
    __syncthreads();
    {
        const int col = lane & 31;
        const int rhi = (lane >> 5) << 2;
        #pragma unroll
        for (int r = 0; r < 16; ++r) {
            const int row = (r & 3) + ((r >> 2) << 3) + rhi;   // verified C/D mapping
            u.red[wv * TBL + row * 32 + col] = acc[r];
        }
    }
    __syncthreads();

    // ---- private table write: live rows only (rows >= K never read by K2);
    //      relaxed agent-scope atomic stores (plain stores proved unsafe
    //      cross-kernel under graph replay) ----
    {
        float* stbl = sums + (size_t)blockIdx.x * TBL;
        const int live = K * 32;             // 672 cells
        for (int cell = tid; cell < live; cell += TPB) {
            const float v = u.red[cell] + u.red[TBL + cell]
                          + u.red[2 * TBL + cell] + u.red[3 * TBL + cell];
            __hip_atomic_store(&stbl[cell], v, __ATOMIC_RELAXED,
                               __HIP_MEMORY_SCOPE_AGENT);
        }
    }
}

// K2: block k reduces its row across all NBLK tables. 1024 threads, 32 table-
// groups; each group owns a CONTIGUOUS run of NBLK/32 tables walked with 8
// independent accumulator streams and unconditional affine loads.
__global__ __launch_bounds__(1024) void msk_final(
    const float* __restrict__ sums,
    const int* __restrict__ gpn,
    int* __restrict__ out,
    int K, int NBLK)
{
    const int G = *gpn;
    const int k = blockIdx.x;
    const int tid = threadIdx.x;
    const int col = tid & 31;
    const int grp = tid >> 5;            // 0..31 table-groups

    const int tpg = NBLK >> 5;           // tables per group (36 at NBLK=1152)
    const int t0  = grp * tpg;
    const size_t rowoff = (size_t)k * 32 + col;

    #define AL(T) __hip_atomic_load(&sums[(size_t)(T) * TBL + rowoff], \
                                    __ATOMIC_RELAXED, __HIP_MEMORY_SCOPE_AGENT)
    float v0 = 0.f, v1 = 0.f, v2 = 0.f, v3 = 0.f;
    float v4 = 0.f, v5 = 0.f, v6 = 0.f, v7 = 0.f;
    int i = 0;
    for (; i + 8 <= tpg; i += 8) {       // unconditional: 8 loads in flight
        v0 += AL(t0 + i + 0); v1 += AL(t0 + i + 1);
        v2 += AL(t0 + i + 2); v3 += AL(t0 + i + 3);
        v4 += AL(t0 + i + 4); v5 += AL(t0 + i + 5);
        v6 += AL(t0 + i + 6); v7 += AL(t0 + i + 7);
    }
    for (; i < tpg; ++i) v0 += AL(t0 + i);
    // leftover tables beyond 32*tpg (NBLK % 32 of them)
    if (grp < (NBLK & 31)) v1 += AL((NBLK & ~31) + grp);
    #undef AL
    const float vv = ((v0 + v1) + (v2 + v3)) + ((v4 + v5) + (v6 + v7));

    __shared__ float P[32][33];
    __shared__ float A[32];
    P[grp][col] = vv;
    __syncthreads();
    if (tid < 32) {
        float s = 0.f;
        #pragma unroll
        for (int g2 = 0; g2 < 32; ++g2) s += P[g2][tid];
        A[tid] = s;
    }
    __syncthreads();

    if (tid == 0) {
        const int GG = (G < 32) ? G : 32;
        float bv; int bg = 0;
        if (GG > 0) {
            bv = A[0];
            for (int g = 1; g < GG; ++g) {
                const float v = A[g];
                if (v > bv) { bv = v; bg = g; }   // strict '>' keeps first index
            }
        }
        out[k] = bg;
    }
}

extern "C" void kernel_launch(void* const* d_in, const int* in_sizes, int n_in,
                              void* d_out, int out_size, void* d_ws, size_t ws_size,
                              hipStream_t stream) {
    const float* seg = (const float*)d_in[0];
    // d_in[1] (prob) does not affect the reference output
    const int* gt  = (const int*)d_in[2];
    const int* gpn = (const int*)d_in[3];

    const int N = in_sizes[1];              // prob is (N,1)
    const int K = in_sizes[0] / N;          // 21
    const int GROWS = in_sizes[2] / N;      // 21
    const int NGROUP = (N + 63) >> 6;       // 4800 64-px groups

    int NBLK = MAXBLK;                      // 1152: wraparound absorbs last 192
    const int minb = (NGROUP + 3) >> 2;
    if (NBLK > minb) NBLK = minb;
    const long long wcap = (long long)(ws_size / (TBL * sizeof(float)));
    if (NBLK > wcap) NBLK = (int)wcap;      // d_ws budget (observed ~256 MB)
    if (NBLK < 1) NBLK = 1;

    msk_main <<<NBLK, TPB, 0, stream>>>(seg, gt, (float*)d_ws,
                                        N, K, GROWS, NGROUP, NBLK);
    msk_final<<<K, 1024, 0, stream>>>((const float*)d_ws, gpn, (int*)d_out,
                                      K, NBLK);
}